// Round 3
// baseline (256.695 us; speedup 1.0000x reference)
//
#include <hip/hip_runtime.h>

// 9x9 box-sum (R=4), zero-padded, over 128 fp32 planes of 512x512.
// Pure streaming: no LDS, no barriers. Thread = 4 cols x 16 rows.
// Horizontal 9-sum in registers from 3 overlapping float4 loads (L1/L2-merged),
// vertical 9-sum via register ring + running sum. 1-row load lookahead.

#define W   512
#define RR  16          // output rows per thread strip
#define NSTRIP (W / RR) // 32

__device__ __forceinline__ float4 ld4(const float* p) { return *(const float4*)p; }
__device__ __forceinline__ float4 add4(float4 a, float4 b) {
    return make_float4(a.x + b.x, a.y + b.y, a.z + b.z, a.w + b.w);
}
__device__ __forceinline__ float4 sub4(float4 a, float4 b) {
    return make_float4(a.x - b.x, a.y - b.y, a.z - b.z, a.w - b.w);
}

__global__ __launch_bounds__(256, 4) void boxfilter9(const float* __restrict__ in,
                                                     float* __restrict__ out) {
    const int t     = threadIdx.x;
    const int unit  = blockIdx.x * 2 + (t >> 7);   // img*NSTRIP + strip (wave-uniform)
    const int img   = unit >> 5;                   // / NSTRIP
    const int strip = unit & (NSTRIP - 1);
    const int cg    = t & 127;
    const int c0    = cg << 2;                     // output col base (multiple of 4)

    const float* __restrict__ inp  = in  + (size_t)img * W * W;
    float* __restrict__       outp = out + (size_t)img * W * W;
    const int  y0    = strip * RR;
    const bool has_l = (c0 >= 4);
    const bool has_r = (c0 + 4 < W);

    // raw 3-load fetch of row y (zero outside image); separated from reduce
    // so the compiler can hoist loads ahead of use
    struct Row3 { float4 a, b, c; };
    auto load_row = [&](int y) -> Row3 {
        Row3 r;
        if ((unsigned)y < W) {                      // wave-uniform branch
            const float* row = inp + y * W;
            r.a = has_l ? ld4(row + c0 - 4) : make_float4(0, 0, 0, 0);
            r.b = ld4(row + c0);
            r.c = has_r ? ld4(row + c0 + 4) : make_float4(0, 0, 0, 0);
        } else {
            r.a = r.b = r.c = make_float4(0, 0, 0, 0);
        }
        return r;
    };
    auto hsum = [&](const Row3& r) -> float4 {
        float4 h;
        float s0 = ((r.a.x + r.a.y) + (r.a.z + r.a.w)) +
                   (((r.b.x + r.b.y) + (r.b.z + r.b.w)) + r.c.x);
        h.x = s0;
        h.y = s0  - r.a.x + r.c.y;
        h.z = h.y - r.a.y + r.c.z;
        h.w = h.z - r.a.z + r.c.w;
        return h;
    };

    // init: ring[0..7] = h(y0-4 .. y0+3), vsum = their sum (8 rows of window)
    float4 ring[9];
    float4 vsum = make_float4(0, 0, 0, 0);
    #pragma unroll
    for (int k = 0; k < 8; ++k) {
        Row3 r = load_row(y0 - 4 + k);
        ring[k] = hsum(r);
        vsum = add4(vsum, ring[k]);
    }

    // 16 output rows, 1-row load lookahead, full unroll -> static ring indices
    Row3 cur = load_row(y0 + 4);
    #pragma unroll
    for (int i = 0; i < RR; ++i) {
        Row3 nxt;
        if (i + 1 < RR) nxt = load_row(y0 + 5 + i);
        float4 hn = hsum(cur);
        float4 o  = add4(vsum, hn);                // 9-row total
        *(float4*)(outp + (size_t)(y0 + i) * W + c0) = o;
        vsum = sub4(o, ring[i % 9]);               // drop top row
        ring[(i + 8) % 9] = hn;
        cur = nxt;
    }
}

extern "C" void kernel_launch(void* const* d_in, const int* in_sizes, int n_in,
                              void* d_out, int out_size, void* d_ws, size_t ws_size,
                              hipStream_t stream) {
    const float* x = (const float*)d_in[0];
    float* y = (float*)d_out;
    // 128 images x 32 strips = 4096 units, 2 units per 256-thread block
    dim3 grid(128 * NSTRIP / 2);
    dim3 block(256);
    boxfilter9<<<grid, block, 0, stream>>>(x, y);
}